// Round 5
// baseline (13.373 us; speedup 1.0000x reference)
//
#include <hip/hip_runtime.h>
#include <math.h>

typedef __attribute__((ext_vector_type(8))) short short8;   // 8 x bf16 (4 VGPR)
typedef __attribute__((ext_vector_type(4))) float f32x4;

#define L2E 1.44269504088896340736f
#define LN2 0.69314718055994530942f

// round-to-nearest-even float -> bf16 bits
static __device__ __forceinline__ unsigned int bfr(float x) {
    union { float f; unsigned u; } v; v.f = x;
    return (v.u + 0x7fffu + ((v.u >> 16) & 1u)) >> 16;
}
static __device__ __forceinline__ unsigned int pk2(float lo, float hi) {
    return bfr(lo) | (bfr(hi) << 16);
}

// out[b,f,co,r] = log( sum_ci w[f,ci,co,r] * exp(ll[b,f,ci,r]) )
// Tile: 16 b x 16 co x 64 ci x 4 r. Grid 2048 = f(128) x bq(4) x ch(4).
// Block 256 = 4 waves; wave w handles r = w. XCD-affine remap keeps the 16
// sub-tiles of each f on one XCD (2 MB/XCD working set -> L2-local refetch).
__global__ __launch_bounds__(256, 6)
void ws_kernel(const float* __restrict__ ll,
               const float* __restrict__ wt,
               float* __restrict__ out)
{
    // E[4r][16b][64ci] bf16 @ 0 (8 KB, plane 2048 B)
    // W[4r][16co][64ci] bf16 @ 8192 (8 KB, plane 2048 B)
    // 128B rows, XOR-swizzle ((row&7)<<4). Obuf [16][68] f32 aliases smem.
    __shared__ char smem[16384];
    float* Obuf = (float*)smem;

    const int t = threadIdx.x;

    // XCD-affine remap: dispatch i -> XCD i%8; each XCD owns 16 whole f's.
    const int i    = blockIdx.x;
    const int tile = (i & 7) * 256 + (i >> 3);
    const int f    = tile >> 4;
    const int sub  = tile & 15;
    const int b0   = (sub >> 2) * 16;
    const int co0  = (sub & 3) * 16;

    // ---- stage E = bf16(exp(ll)) : thread owns (b, ci-pair), 2 b's ----
    {
        const float4* llv = (const float4*)ll;
        const int c  = t & 31;           // ci = 2c, 2c+1
        const int bb = t >> 5;           // 0..7
        #pragma unroll
        for (int k = 0; k < 2; ++k) {
            const int b = bb + 8 * k;    // 0..15
            const size_t base = (size_t)(b0 + b) * 8192 + (size_t)f * 64 + 2 * c;
            float4 v0 = llv[base];       // r=0..3 of ci=2c
            float4 v1 = llv[base + 1];   // r=0..3 of ci=2c+1
            float e0x = exp2f(v0.x * L2E), e0y = exp2f(v0.y * L2E),
                  e0z = exp2f(v0.z * L2E), e0w = exp2f(v0.w * L2E);
            float e1x = exp2f(v1.x * L2E), e1y = exp2f(v1.y * L2E),
                  e1z = exp2f(v1.z * L2E), e1w = exp2f(v1.w * L2E);
            const int off = (c * 4) ^ ((b & 7) << 4);
            char* rowp = smem + b * 128 + off;
            *(unsigned*)(rowp)        = pk2(e0x, e1x);   // r=0 plane (2 KB each)
            *(unsigned*)(rowp + 2048) = pk2(e0y, e1y);
            *(unsigned*)(rowp + 4096) = pk2(e0z, e1z);
            *(unsigned*)(rowp + 6144) = pk2(e0w, e1w);
        }
    }
    // ---- stage Wt = bf16(w) -> [co][ci] : thread owns (co j = t&15, ci-quad cq = t>>4) ----
    {
        const float4* wv = (const float4*)wt;
        const int j  = t & 15;           // co_local
        const int cq = t >> 4;           // 0..15 ; ci = 4cq + i
        const size_t base = (size_t)f * 4096 + (size_t)(4 * cq) * 64 + co0 + j;
        float4 q0 = wv[base];
        float4 q1 = wv[base + 64];
        float4 q2 = wv[base + 128];
        float4 q3 = wv[base + 192];
        const int off = (cq * 8) ^ ((j & 7) << 4);
        char* rowp = smem + 8192 + j * 128 + off;    // r=0 plane; planes 2 KB apart
        *(uint2*)(rowp)        = make_uint2(pk2(q0.x, q1.x), pk2(q2.x, q3.x));
        *(uint2*)(rowp + 2048) = make_uint2(pk2(q0.y, q1.y), pk2(q2.y, q3.y));
        *(uint2*)(rowp + 4096) = make_uint2(pk2(q0.z, q1.z), pk2(q2.z, q3.z));
        *(uint2*)(rowp + 6144) = make_uint2(pk2(q0.w, q1.w), pk2(q2.w, q3.w));
    }
    __syncthreads();

    // ---- MFMA: wave r computes C[16b x 16co] = E_r(16x64) . Wt_r^T(64x16) ----
    const int r  = t >> 6;
    const int l  = t & 63;
    const int lr = l & 15;     // A-row (b) / B-col (co) within 16-tile
    const int lg = l >> 4;     // k-group (8 contiguous k each)
    const char* Ep = smem + r * 2048;
    const char* Wp = smem + 8192 + r * 2048;

    f32x4 acc = {0.f, 0.f, 0.f, 0.f};
    const int swz = (lr & 7) << 4;
    #pragma unroll
    for (int kt = 0; kt < 2; ++kt) {
        const int sb = ((kt * 4 + lg) * 16) ^ swz;
        short8 a0 = *(const short8*)(Ep + lr * 128 + sb);
        short8 w0 = *(const short8*)(Wp + lr * 128 + sb);
        acc = __builtin_amdgcn_mfma_f32_16x16x32_bf16(a0, w0, acc, 0, 0, 0);
    }

    __syncthreads();   // operand LDS dead before Obuf overwrite

    // ---- epilogue: log(acc) -> Obuf[b][co_local*4+r] (rows 68 dwords) ----
    // D layout (m89): col = lr (co), row = lg*4 + v (b)
    #pragma unroll
    for (int v = 0; v < 4; ++v) {
        Obuf[(lg * 4 + v) * 68 + lr * 4 + r] = __log2f(acc[v]) * LN2;
    }
    __syncthreads();

    // ---- coalesced stores: 16 rows x 16 float4 (256 B per b-row quarter) ----
    {
        const int b = t >> 4;            // 0..15
        const int j = t & 15;            // float4 column within 16-co quarter
        float4 vv = *(const float4*)&Obuf[b * 68 + j * 4];
        *(float4*)(out + ((size_t)(b0 + b) * 128 + f) * 256 + co0 * 4 + j * 4) = vv;
    }
}

extern "C" void kernel_launch(void* const* d_in, const int* in_sizes, int n_in,
                              void* d_out, int out_size, void* d_ws, size_t ws_size,
                              hipStream_t stream)
{
    const float* ll = (const float*)d_in[0];
    const float* wt = (const float*)d_in[1];
    float* out = (float*)d_out;
    hipLaunchKernelGGL(ws_kernel, dim3(2048), dim3(256), 0, stream, ll, wt, out);
}

// Round 6
// 10.738 us; speedup vs baseline: 1.2454x; 1.2454x over previous
//
#include <hip/hip_runtime.h>
#include <hip/hip_bf16.h>
#include <math.h>

typedef __attribute__((ext_vector_type(8))) short short8;   // 8 x bf16 (4 VGPR)
typedef __attribute__((ext_vector_type(4))) float f32x4;

#define L2E 1.44269504088896340736f
#define LN2 0.69314718055994530942f

// pack (lo,hi) -> bf16x2 via native v_cvt_pk_bf16_f32 (RNE)
static __device__ __forceinline__ unsigned pk2(float lo, float hi) {
    __hip_bfloat162 h = __float22bfloat162_rn(make_float2(lo, hi));
    union { __hip_bfloat162 h2; unsigned u; } cv; cv.h2 = h;
    return cv.u;
}

// out[b,f,co,r] = log( sum_ci w[f,ci,co,r] * exp(ll[b,f,ci,r]) )
// Tile: 16 b x 64 co x 64 ci x 4 r. Grid 512 = f(128) x bq(4), block 512 = 8 waves.
// Wave w: r = w&3, co-half = w>>2. ll fetched/exp'd once; wt raw 4x/f but
// XCD-affine remap keeps the 4 sharers on one XCD -> L2-local.
__global__ __launch_bounds__(512, 4)
void ws_kernel(const float* __restrict__ ll,
               const float* __restrict__ wt,
               float* __restrict__ out)
{
    // E[4r][16b][64ci] bf16 @ 0 (8 KB, plane 2048 B)
    // W[4r][64co][64ci] bf16 @ 8192 (32 KB, plane 8192 B)
    // Obuf [16][260] f32 @ 40960 (16.6 KB) -- separate region, no alias barrier
    __shared__ char smem[8192 + 32768 + 16640];
    float* Obuf = (float*)(smem + 8192 + 32768);

    const int t = threadIdx.x;

    // XCD-affine remap: dispatch i -> XCD i%8; each XCD owns 16 whole f's.
    const int i    = blockIdx.x;
    const int tile = (i & 7) * 64 + (i >> 3);
    const int f    = tile >> 2;
    const int b0   = (tile & 3) * 16;

    // ================= issue ALL global loads up front (T14) =================
    const float4* llv = (const float4*)ll;
    const int c = t & 31;            // ci pair = 2c, 2c+1
    const int b = t >> 5;            // 0..15
    const size_t ebase = (size_t)(b0 + b) * 8192 + (size_t)f * 64 + 2 * c;
    float4 v0 = llv[ebase];          // r=0..3 of ci=2c
    float4 v1 = llv[ebase + 1];      // r=0..3 of ci=2c+1

    const float4* wv = (const float4*)wt;
    const int j  = t & 63;           // co_local
    const int c8 = t >> 6;           // ci-oct
    const size_t wbase = (size_t)f * 4096 + (size_t)(8 * c8) * 64 + j;
    float4 q00 = wv[wbase];          // ci = 8c8+0
    float4 q01 = wv[wbase + 64];
    float4 q02 = wv[wbase + 128];
    float4 q03 = wv[wbase + 192];
    float4 q10 = wv[wbase + 256];
    float4 q11 = wv[wbase + 320];
    float4 q12 = wv[wbase + 384];
    float4 q13 = wv[wbase + 448];

    // ================= process E (arrives first) =================
    {
        float e0x = exp2f(v0.x * L2E), e0y = exp2f(v0.y * L2E),
              e0z = exp2f(v0.z * L2E), e0w = exp2f(v0.w * L2E);
        float e1x = exp2f(v1.x * L2E), e1y = exp2f(v1.y * L2E),
              e1z = exp2f(v1.z * L2E), e1w = exp2f(v1.w * L2E);
        const int off = (c * 4) ^ ((b & 7) << 4);
        char* rowp = smem + b * 128 + off;
        *(unsigned*)(rowp)        = pk2(e0x, e1x);   // r=0 plane (2 KB each)
        *(unsigned*)(rowp + 2048) = pk2(e0y, e1y);
        *(unsigned*)(rowp + 4096) = pk2(e0z, e1z);
        *(unsigned*)(rowp + 6144) = pk2(e0w, e1w);
    }
    // ================= process W =================
    {
        const int off = (c8 * 16) ^ ((j & 7) << 4);
        char* rowp = smem + 8192 + j * 128 + off;   // r=0 plane; planes 8 KB apart
        uint4 u;
        u.x = pk2(q00.x, q01.x); u.y = pk2(q02.x, q03.x);
        u.z = pk2(q10.x, q11.x); u.w = pk2(q12.x, q13.x);
        *(uint4*)(rowp) = u;
        u.x = pk2(q00.y, q01.y); u.y = pk2(q02.y, q03.y);
        u.z = pk2(q10.y, q11.y); u.w = pk2(q12.y, q13.y);
        *(uint4*)(rowp + 8192) = u;
        u.x = pk2(q00.z, q01.z); u.y = pk2(q02.z, q03.z);
        u.z = pk2(q10.z, q11.z); u.w = pk2(q12.z, q13.z);
        *(uint4*)(rowp + 16384) = u;
        u.x = pk2(q00.w, q01.w); u.y = pk2(q02.w, q03.w);
        u.z = pk2(q10.w, q11.w); u.w = pk2(q12.w, q13.w);
        *(uint4*)(rowp + 24576) = u;
    }
    __syncthreads();

    // ---- MFMA: wave (r, coh) computes C[16b x 32co] = E_r(16x64) . Wt_r^T(64x32) ----
    const int w   = t >> 6;
    const int l   = t & 63;
    const int r   = w & 3;
    const int coh = w >> 2;
    const int lr  = l & 15;     // A-row (b) / B-col (co) within 16-tile
    const int lg  = l >> 4;     // k-group (8 contiguous k each)
    const char* Ep = smem + r * 2048;
    const char* Wp = smem + 8192 + r * 8192 + coh * 4096;

    f32x4 acc[2] = {{0.f,0.f,0.f,0.f},{0.f,0.f,0.f,0.f}};
    const int swz = (lr & 7) << 4;
    #pragma unroll
    for (int kt = 0; kt < 2; ++kt) {
        const int sb = ((kt * 4 + lg) * 16) ^ swz;
        short8 a0 = *(const short8*)(Ep + lr * 128 + sb);
        short8 w0 = *(const short8*)(Wp + lr * 128 + sb);
        short8 w1 = *(const short8*)(Wp + (lr + 16) * 128 + sb);
        acc[0] = __builtin_amdgcn_mfma_f32_16x16x32_bf16(a0, w0, acc[0], 0, 0, 0);
        acc[1] = __builtin_amdgcn_mfma_f32_16x16x32_bf16(a0, w1, acc[1], 0, 0, 0);
    }

    // ---- epilogue: log(acc) -> Obuf[b][co*4+r] (rows 260 dwords, own region) ----
    // D layout (m89): col = lr (co), row = lg*4 + v (b)
    #pragma unroll
    for (int nt = 0; nt < 2; ++nt) {
        #pragma unroll
        for (int v = 0; v < 4; ++v) {
            Obuf[(lg * 4 + v) * 260 + ((coh * 32 + nt * 16 + lr) * 4 + r)] =
                __log2f(acc[nt][v]) * LN2;
        }
    }
    __syncthreads();

    // ---- coalesced stores: each wave writes two full 1 KB (b,f)-rows ----
    #pragma unroll
    for (int k = 0; k < 2; ++k) {
        const int bb = w * 2 + k;
        float4 vv = *(const float4*)&Obuf[bb * 260 + l * 4];
        *(float4*)(out + ((size_t)(b0 + bb) * 128 + f) * 256 + l * 4) = vv;
    }
}

extern "C" void kernel_launch(void* const* d_in, const int* in_sizes, int n_in,
                              void* d_out, int out_size, void* d_ws, size_t ws_size,
                              hipStream_t stream)
{
    const float* ll = (const float*)d_in[0];
    const float* wt = (const float*)d_in[1];
    float* out = (float*)d_out;
    hipLaunchKernelGGL(ws_kernel, dim3(512), dim3(512), 0, stream, ll, wt, out);
}

// Round 7
// 10.626 us; speedup vs baseline: 1.2586x; 1.0106x over previous
//
#include <hip/hip_runtime.h>
#include <hip/hip_bf16.h>
#include <math.h>

typedef __attribute__((ext_vector_type(8))) short short8;   // 8 x bf16 (4 VGPR)
typedef __attribute__((ext_vector_type(4))) float f32x4;

#define L2E 1.44269504088896340736f
#define LN2 0.69314718055994530942f

// pack (lo,hi) -> bf16x2 (RNE, native v_cvt_pk_bf16_f32)
static __device__ __forceinline__ unsigned pk2(float lo, float hi) {
    __hip_bfloat162 h = __float22bfloat162_rn(make_float2(lo, hi));
    union { __hip_bfloat162 h2; unsigned u; } cv; cv.h2 = h;
    return cv.u;
}

// out[b,f,co,r] = log( sum_ci w[f,ci,co,r] * exp(ll[b,f,ci,r]) )
// Grid 256 = 1 block/CU; block 512 = 8 waves, wave w: (r = w&3, coh = w>>2).
// Each block: one f, two 16b x 64co tiles (b0, b0+16). W staged ONCE (wt raw
// traffic 2x not 4x); E1 load + tile0 store overlap tile0/tile1 compute.
__global__ __launch_bounds__(512, 2)
void ws_kernel(const float* __restrict__ ll,
               const float* __restrict__ wt,
               float* __restrict__ out)
{
    // LDS (64 KB exactly):
    //  E0 @0      8 KB : bf16 exp(ll) tile0; planes r (2 KB), rows b 128 B, XOR (b&7)<<4
    //  E1 @8192   8 KB : tile1, same layout
    //  W  @16384 32 KB : bf16 w^T; planes r (8 KB), rows co 128 B, XOR (co&7)<<4
    //  Obuf @49152 16 KB : f32 [r][16b][64co], co XOR'd by (b>>2)<<3
    //    writes (epi): banks = co' mod 32; lanes span 4 lg x 16 lr; lg flips co
    //    bits 3..4 -> 32 banks x 2 lanes = 2-way (free). gather reads: l^const
    //    stride-1 -> 2-way (free).
    __shared__ char smem[65536];
    float* Obuf = (float*)(smem + 49152);

    const int t = threadIdx.x;

    // XCD-affine remap: XCD x = i&7 owns f in [16x,16x+16).
    const int i  = blockIdx.x;
    const int x  = i & 7;
    const int k  = i >> 3;          // 0..31
    const int f  = x * 16 + (k >> 1);
    const int b0 = (k & 1) * 32;    // tile0: b0 ; tile1: b0+16

    // ================= issue ALL global loads (E0, W, E1) =================
    const float4* llv = (const float4*)ll;
    const int c = t & 31;           // ci pair = 2c, 2c+1
    const int b = t >> 5;           // 0..15
    const size_t e0 = (size_t)(b0 + b) * 8192 + (size_t)f * 64 + 2 * c;
    float4 v0 = llv[e0];            // tile0, r=0..3 of ci=2c
    float4 v1 = llv[e0 + 1];

    const float4* wv = (const float4*)wt;
    const int j  = t & 63;          // co
    const int c8 = t >> 6;          // ci-oct
    const size_t wb = (size_t)f * 4096 + (size_t)(8 * c8) * 64 + j;
    float4 q00 = wv[wb];
    float4 q01 = wv[wb + 64];
    float4 q02 = wv[wb + 128];
    float4 q03 = wv[wb + 192];
    float4 q10 = wv[wb + 256];
    float4 q11 = wv[wb + 320];
    float4 q12 = wv[wb + 384];
    float4 q13 = wv[wb + 448];

    float4 u0 = llv[e0 + 131072];   // tile1 (b + 16)
    float4 u1 = llv[e0 + 131073];

    // ================= stage E0 =================
    {
        float e0x = exp2f(v0.x * L2E), e0y = exp2f(v0.y * L2E),
              e0z = exp2f(v0.z * L2E), e0w = exp2f(v0.w * L2E);
        float e1x = exp2f(v1.x * L2E), e1y = exp2f(v1.y * L2E),
              e1z = exp2f(v1.z * L2E), e1w = exp2f(v1.w * L2E);
        const int off = (c * 4) ^ ((b & 7) << 4);
        char* rowp = smem + b * 128 + off;
        *(unsigned*)(rowp)        = pk2(e0x, e1x);
        *(unsigned*)(rowp + 2048) = pk2(e0y, e1y);
        *(unsigned*)(rowp + 4096) = pk2(e0z, e1z);
        *(unsigned*)(rowp + 6144) = pk2(e0w, e1w);
    }
    // ================= stage W (once) =================
    {
        const int off = (c8 * 16) ^ ((j & 7) << 4);
        char* rowp = smem + 16384 + j * 128 + off;
        uint4 u;
        u.x = pk2(q00.x, q01.x); u.y = pk2(q02.x, q03.x);
        u.z = pk2(q10.x, q11.x); u.w = pk2(q12.x, q13.x);
        *(uint4*)(rowp) = u;
        u.x = pk2(q00.y, q01.y); u.y = pk2(q02.y, q03.y);
        u.z = pk2(q10.y, q11.y); u.w = pk2(q12.y, q13.y);
        *(uint4*)(rowp + 8192) = u;
        u.x = pk2(q00.z, q01.z); u.y = pk2(q02.z, q03.z);
        u.z = pk2(q10.z, q11.z); u.w = pk2(q12.z, q13.z);
        *(uint4*)(rowp + 16384) = u;
        u.x = pk2(q00.w, q01.w); u.y = pk2(q02.w, q03.w);
        u.z = pk2(q10.w, q11.w); u.w = pk2(q12.w, q13.w);
        *(uint4*)(rowp + 24576) = u;
    }
    __syncthreads();   // bar1: E0, W visible

    const int w   = t >> 6;
    const int l   = t & 63;
    const int r   = w & 3;
    const int coh = w >> 2;
    const int lr  = l & 15;
    const int lg  = l >> 4;
    const int swz = (lr & 7) << 4;
    const char* Wp = smem + 16384 + r * 8192 + coh * 4096;

    // ---- tile0 MFMA ----
    f32x4 acc0[2] = {{0.f,0.f,0.f,0.f},{0.f,0.f,0.f,0.f}};
    {
        const char* Ep = smem + r * 2048;
        #pragma unroll
        for (int kt = 0; kt < 2; ++kt) {
            const int sb = ((kt * 4 + lg) * 16) ^ swz;
            short8 a0 = *(const short8*)(Ep + lr * 128 + sb);
            short8 w0 = *(const short8*)(Wp + lr * 128 + sb);
            short8 w1 = *(const short8*)(Wp + (lr + 16) * 128 + sb);
            acc0[0] = __builtin_amdgcn_mfma_f32_16x16x32_bf16(a0, w0, acc0[0], 0, 0, 0);
            acc0[1] = __builtin_amdgcn_mfma_f32_16x16x32_bf16(a0, w1, acc0[1], 0, 0, 0);
        }
    }
    // ---- tile0 epilogue -> Obuf ----
    // D layout (m89): col(co) = lr, row(b) = lg*4 + v
    #pragma unroll
    for (int nt = 0; nt < 2; ++nt) {
        #pragma unroll
        for (int v = 0; v < 4; ++v) {
            const int bl = lg * 4 + v;
            const int co = (coh * 32 + nt * 16 + lr) ^ (lg << 3);
            Obuf[r * 1024 + bl * 64 + co] = __log2f(acc0[nt][v]) * LN2;
        }
    }
    // ---- stage E1 (overlaps tile0 compute) ----
    {
        float e0x = exp2f(u0.x * L2E), e0y = exp2f(u0.y * L2E),
              e0z = exp2f(u0.z * L2E), e0w = exp2f(u0.w * L2E);
        float e1x = exp2f(u1.x * L2E), e1y = exp2f(u1.y * L2E),
              e1z = exp2f(u1.z * L2E), e1w = exp2f(u1.w * L2E);
        const int off = (c * 4) ^ ((b & 7) << 4);
        char* rowp = smem + 8192 + b * 128 + off;
        *(unsigned*)(rowp)        = pk2(e0x, e1x);
        *(unsigned*)(rowp + 2048) = pk2(e0y, e1y);
        *(unsigned*)(rowp + 4096) = pk2(e0z, e1z);
        *(unsigned*)(rowp + 6144) = pk2(e0w, e1w);
    }
    __syncthreads();   // bar2: Obuf(tile0) + E1 visible

    // ---- tile0 store (gather Obuf) + tile1 MFMA ----
    #pragma unroll
    for (int kk = 0; kk < 2; ++kk) {
        const int bb = w * 2 + kk;
        const int sx = (bb >> 2) << 3;
        const int idx = bb * 64 + (l ^ sx);
        float4 vv;
        vv.x = Obuf[idx];
        vv.y = Obuf[idx + 1024];
        vv.z = Obuf[idx + 2048];
        vv.w = Obuf[idx + 3072];
        *(float4*)(out + ((size_t)(b0 + bb) * 128 + f) * 256 + l * 4) = vv;
    }

    f32x4 acc1[2] = {{0.f,0.f,0.f,0.f},{0.f,0.f,0.f,0.f}};
    {
        const char* Ep = smem + 8192 + r * 2048;
        #pragma unroll
        for (int kt = 0; kt < 2; ++kt) {
            const int sb = ((kt * 4 + lg) * 16) ^ swz;
            short8 a0 = *(const short8*)(Ep + lr * 128 + sb);
            short8 w0 = *(const short8*)(Wp + lr * 128 + sb);
            short8 w1 = *(const short8*)(Wp + (lr + 16) * 128 + sb);
            acc1[0] = __builtin_amdgcn_mfma_f32_16x16x32_bf16(a0, w0, acc1[0], 0, 0, 0);
            acc1[1] = __builtin_amdgcn_mfma_f32_16x16x32_bf16(a0, w1, acc1[1], 0, 0, 0);
        }
    }
    __syncthreads();   // bar3: tile0 Obuf reads done (epi1 may overwrite)

    // ---- tile1 epilogue -> Obuf ----
    #pragma unroll
    for (int nt = 0; nt < 2; ++nt) {
        #pragma unroll
        for (int v = 0; v < 4; ++v) {
            const int bl = lg * 4 + v;
            const int co = (coh * 32 + nt * 16 + lr) ^ (lg << 3);
            Obuf[r * 1024 + bl * 64 + co] = __log2f(acc1[nt][v]) * LN2;
        }
    }
    __syncthreads();   // bar4: Obuf(tile1) visible

    // ---- tile1 store ----
    #pragma unroll
    for (int kk = 0; kk < 2; ++kk) {
        const int bb = w * 2 + kk;
        const int sx = (bb >> 2) << 3;
        const int idx = bb * 64 + (l ^ sx);
        float4 vv;
        vv.x = Obuf[idx];
        vv.y = Obuf[idx + 1024];
        vv.z = Obuf[idx + 2048];
        vv.w = Obuf[idx + 3072];
        *(float4*)(out + ((size_t)(b0 + 16 + bb) * 128 + f) * 256 + l * 4) = vv;
    }
}

extern "C" void kernel_launch(void* const* d_in, const int* in_sizes, int n_in,
                              void* d_out, int out_size, void* d_ws, size_t ws_size,
                              hipStream_t stream)
{
    const float* ll = (const float*)d_in[0];
    const float* wt = (const float*)d_in[1];
    float* out = (float*)d_out;
    hipLaunchKernelGGL(ws_kernel, dim3(256), dim3(512), 0, stream, ll, wt, out);
}